// Round 18
// baseline (149.826 us; speedup 1.0000x reference)
//
#include <hip/hip_runtime.h>
#include <hip/hip_bf16.h>

// ================= problem constants =================
#define BB 8
#define NN 1024
#define HH 768
#define NHD 12
#define ASZ 64
#define MM 256
#define QSCALE 0.125f   // AS^-0.5
#define NSLOPE 0.02f
#define LOG2E 1.44269504f
#define PRMAX 384       // padded predicate rows per batch

typedef __attribute__((ext_vector_type(8))) short bf16x8;
typedef __attribute__((ext_vector_type(4))) float f32x4;

#define EXP2F(x) __builtin_amdgcn_exp2f(x)
#define RCPF(x)  __builtin_amdgcn_rcpf(x)

// ============ workspace layout (byte offsets, all 16B-aligned) ============
#define OFFB_QB    ((size_t)0)            // 8*1024*768 bf16
#define OFFB_KB    ((size_t)12582912)
#define OFFB_VB    ((size_t)25165824)     // V^T: [b][h][d][n] bf16
#define OFFB_XB    ((size_t)37748736)     // x in bf16
#define OFFB_WQB   ((size_t)50331648)     // 768*768 bf16
#define OFFB_WKB   ((size_t)51511296)
#define OFFB_WVB   ((size_t)52690944)
#define OFFB_WVAR  ((size_t)53870592)     // W_var bf16
#define OFFB_WSYM  ((size_t)55050240)     // W_sym bf16
#define OFFB_SRAW  ((size_t)56229888)     // 8192 f32
#define OFFB_DIAG  ((size_t)56262656)     // 8192 f32
#define OFFB_BIAS4 ((size_t)56295424)     // 8192 float4
#define OFFB_PLIST ((size_t)56426496)     // 8192 i32
#define OFFB_PCNT  ((size_t)56459264)
#define OFFB_SUMW  ((size_t)56459296)
#define OFFB_ZZ    ((size_t)56459328)     // 2*8*768 f32
#define OFFB_TV    ((size_t)56508480)
#define OFFB_PM    ((size_t)56557632)
#define OFFB_VROWS ((size_t)56582208)     // 8*384*768 bf16 gathered var rows

__device__ __forceinline__ float lrelu(float v) { return v >= 0.f ? v : NSLOPE * v; }

__device__ __forceinline__ ushort f2bf(float f) {  // round-half-up f32->bf16 (2 ops)
  return (ushort)((__float_as_uint(f) + 0x8000u) >> 16);
}
__device__ __forceinline__ float bf2f(ushort u) {
  union { unsigned u; float f; } v; v.u = (unsigned)u << 16;
  return v.f;
}
__device__ __forceinline__ unsigned packbf2(float lo, float hi) {  // (bf(hi)<<16)|bf(lo)
  unsigned a = __float_as_uint(hi) + 0x8000u;
  unsigned b = __float_as_uint(lo) + 0x8000u;
  return __builtin_amdgcn_perm(a, b, 0x07060302u);
}
__device__ __forceinline__ float fast_tanh(float x) {  // exp2-domain, saturates to +-1
  float e = EXP2F(x * (2.f * LOG2E));
  return 1.f - 2.f * RCPF(e + 1.f);
}

// weights for the final weighted row-sums of y (derived from pm algebra).
__device__ __forceinline__ void coefs(const int* ppb, int j, float& c1, float& c2) {
  auto pred = [&](int tt) { return tt >= 0 && tt < NN && ppb[tt] == 1; };
  auto single = [&](int tt) { return tt == 0 || (tt >= 2 && ppb[tt - 2] == 1); };
  auto wgt = [&](int tt) {
    if (!pred(tt)) return 0.f;
    bool tri = (tt >= 1) && (tt <= 1 || !single(tt));
    return tri ? 3.f : 2.f;
  };
  float a = 0.f;
  if (pred(j + 1)) a += wgt(j + 1) * (single(j + 1) ? 0.f : 0.5f);
  if (j >= 1 && pred(j - 1)) a += wgt(j - 1) * (single(j - 1) ? 1.f : 0.5f);
  c1 = a;
  c2 = wgt(j);
}

// ============ K_pred: compact predicate list + sum of weights + ws zeroing ============
__global__ void k_pred(const int* __restrict__ pp, int* __restrict__ plist,
                       int* __restrict__ pcnt, float* __restrict__ sumw,
                       float* __restrict__ sraw, float* __restrict__ diag,
                       float* __restrict__ zz) {
  int b = blockIdx.x;
  int lane = threadIdx.x;  // blockDim 64
  const int* ppb = pp + b * NN;
  int base = 0;
  float wacc = 0.f;
  for (int c = 0; c < NN; c += 64) {
    int i = c + lane;
    bool isp = ppb[i] == 1;
    unsigned long long mask = __ballot(isp);
    if (isp) {
      int pos = base + __popcll(mask & ((1ull << lane) - 1ull));
      plist[b * NN + pos] = i;
      bool sing = (i == 0) || (i >= 2 && ppb[i - 2] == 1);
      bool tri = (i >= 1) && (i <= 1 || !sing);
      wacc += tri ? 3.f : 2.f;
    }
    base += __popcll(mask);
  }
  for (int off = 32; off; off >>= 1) wacc += __shfl_xor(wacc, off);
  if (lane == 0) { pcnt[b] = base; sumw[b] = wacc; }
  for (int c = lane; c < NN; c += 64) { sraw[b * NN + c] = 0.f; diag[b * NN + c] = 0.f; }
  for (int c = lane; c < HH; c += 64) {
    zz[b * HH + c] = 0.f;
    zz[BB * HH + b * HH + c] = 0.f;
  }
}

// ============ K_cvtall: x + 5 weights f32->bf16, plus cross scores ============
#define NXQ (BB * NN * HH / 4)      // 1572864
#define WQ  (HH * HH / 4)           // 147456
#define NCVT ((NXQ + 5 * WQ) / 256) // 9024
__global__ void k_cvtall(const float* __restrict__ x,
                         const float* __restrict__ s1, const float* __restrict__ s2,
                         const float* __restrict__ s3, const float* __restrict__ s4,
                         const float* __restrict__ s5,
                         ushort* __restrict__ dx,
                         ushort* __restrict__ d1, ushort* __restrict__ d2,
                         ushort* __restrict__ d3, ushort* __restrict__ d4,
                         ushort* __restrict__ d5,
                         const int* __restrict__ occ, const float* __restrict__ Wc,
                         const float* __restrict__ bc, float* __restrict__ diag) {
  if (blockIdx.x < NCVT) {
    int idx = blockIdx.x * 256 + threadIdx.x;
    const float* src; ushort* dst; int off;
    if (idx < NXQ) { src = x; dst = dx; off = idx; }
    else {
      int r = idx - NXQ;
      int z = r / WQ;
      off = r - z * WQ;
      src = z == 0 ? s1 : z == 1 ? s2 : z == 2 ? s3 : z == 3 ? s4 : s5;
      dst = z == 0 ? d1 : z == 1 ? d2 : z == 2 ? d3 : z == 3 ? d4 : d5;
    }
    float4 v = ((const float4*)src)[off];
    ushort4 o;
    o.x = f2bf(v.x); o.y = f2bf(v.y); o.z = f2bf(v.z); o.w = f2bf(v.w);
    ((ushort4*)dst)[off] = o;
  } else {
    int g = (blockIdx.x - NCVT) * 4 + (threadIdx.x >> 6);
    int lane = threadIdx.x & 63;
    int b = g >> 8, m = g & (MM - 1);
    int o0 = occ[(b * MM + m) * 2 + 0];
    int o1 = occ[(b * MM + m) * 2 + 1];
    const float* x0 = x + (size_t)(b * NN + o0) * HH;
    const float* x1 = x + (size_t)(b * NN + o1) * HH;
    float acc = 0.f;
    for (int d = lane; d < HH; d += 64) acc += 0.5f * (x0[d] + x1[d]) * Wc[d];
    for (int off = 32; off; off >>= 1) acc += __shfl_xor(acc, off);
    if (lane == 0) {
      float sc = lrelu(acc + bc[0]);
      float sq = sc * sc;
      diag[b * NN + o0] = sq;
      diag[b * NN + o1] = sq;
    }
  }
}

// ============ K_gather: compact var_in rows (bf16) for the score GEMM ============
__global__ void k_gather(const ushort* __restrict__ xb, const int* __restrict__ pp,
                         const int* __restrict__ plist, const int* __restrict__ pcnt,
                         ushort* __restrict__ vrows) {
  int b = blockIdx.y;
  int j = blockIdx.x * 4 + (threadIdx.x >> 6);
  int lane = threadIdx.x & 63;
  if (j >= pcnt[b]) return;
  int i = plist[b * NN + j];
  bool sing = (i == 0) || (i >= 2 && pp[b * NN + i - 2] == 1);
  float wa = sing ? 0.f : 0.5f, wb = sing ? 1.f : 0.5f;
  const ushort* rp = xb + (size_t)(b * NN + ((i - 1) & (NN - 1))) * HH;
  const ushort* rn = xb + (size_t)(b * NN + ((i + 1) & (NN - 1))) * HH;
  ushort* dst = vrows + ((size_t)b * PRMAX + j) * HH;
#pragma unroll
  for (int it = 0; it < 3; ++it) {
    int d4 = lane + it * 64;
    ushort4 p4 = ((const ushort4*)rp)[d4];
    ushort4 n4 = ((const ushort4*)rn)[d4];
    ushort4 o;
    o.x = f2bf(wa * bf2f(p4.x) + wb * bf2f(n4.x));
    o.y = f2bf(wa * bf2f(p4.y) + wb * bf2f(n4.y));
    o.z = f2bf(wa * bf2f(p4.z) + wb * bf2f(n4.z));
    o.w = f2bf(wa * bf2f(p4.w) + wb * bf2f(n4.w));
    ((ushort4*)dst)[d4] = o;
  }
}

// ============ K_bias: per-row sparse bias window (log2e-scaled for exp2 softmax) ============
__global__ void k_bias(const int* __restrict__ pp, const float* __restrict__ s_raw,
                       const float* __restrict__ diag, const float* __restrict__ b_score,
                       float4* __restrict__ bias4) {
  int g = blockIdx.x * 256 + threadIdx.x;
  int b = g >> 10, r = g & (NN - 1);
  const int* ppb = pp + b * NN;
  int i = -1;
  if (ppb[r] == 1) i = r;
  else if (r + 1 < NN && ppb[r + 1] == 1) i = r + 1;
  else if (r >= 1 && ppb[r - 1] == 1) i = r - 1;
  float v0 = 0.f, v1 = 0.f, v2 = 0.f; int cw = r;
  if (i >= 1 && i + 1 < NN) {
    float s = lrelu(s_raw[b * NN + i] + b_score[0]);
    float s2 = s * s;
    cw = i - 1;
    if (i == r) { v0 = 0.2f * s; v1 = 1.6f * s2; v2 = 0.2f * s; }
    else       { v0 = 0.8f * s2; v1 = 0.2f * s; v2 = 0.8f * s2; }
  }
  int slot = r - cw;
  float d = diag[g];
  if (slot == 0) v0 += d; else if (slot == 1) v1 += d; else v2 += d;
  bias4[g] = make_float4(__int_as_float(cw), v0 * LOG2E, v1 * LOG2E, v2 * LOG2E);
}

// ============ K_mats: fused {QKV GEMM (1152)} + {score GEMM (576)} ============
// GEMM path: 2-deep register prefetch (A/B sets, compile-time selection).
#define GEMM_BLKS 1152
#define MATS_BLKS 1728
__global__ __launch_bounds__(256, 2) void k_mats(
    const ushort* __restrict__ X, const ushort* __restrict__ vrows,
    const int* __restrict__ plist, const int* __restrict__ pcnt,
    const ushort* __restrict__ Wvar, const ushort* __restrict__ Wsym,
    const float* __restrict__ bvar, const float* __restrict__ bsym,
    const float* __restrict__ wscore, float* __restrict__ s_raw,
    const ushort* __restrict__ W0, const ushort* __restrict__ W1, const ushort* __restrict__ W2,
    const float* __restrict__ b0, const float* __restrict__ b1, const float* __restrict__ b2,
    ushort* __restrict__ C0, ushort* __restrict__ C1, ushort* __restrict__ C2) {
  __shared__ ushort Sm[16384];   // 32 KB carve
  __shared__ int pl[64];
  __shared__ float red[64];
  const int bid = blockIdx.x;    // natural order (XCD swizzle measured harmful)
  const int t = threadIdx.x;
  const int w = t >> 6, lane = t & 63, lg = lane >> 4, lm = lane & 15;
  const int r0 = t >> 3, c = t & 7;
  const int ssw = (c ^ (r0 & 7)) * 8;
  if (bid < GEMM_BLKS) {
    // ---------------- QKV GEMM path (2-deep prefetch) ----------------
    const int z = bid / 384;
    const int r = bid % 384;
    const int m0 = (r & 63) * 128, n0 = (r >> 6) * 128;
    const ushort* W = z == 0 ? W0 : (z == 1 ? W1 : W2);
    const float* bias = z == 0 ? b0 : (z == 1 ? b1 : b2);
    ushort* C = z == 0 ? C0 : (z == 1 ? C1 : C2);
    const float alpha = z == 0 ? QSCALE * LOG2E : 1.f;
    ushort* As = Sm;
    ushort* Bs = Sm + 8192;
    const int wm = (w >> 1) * 64, wn = (w & 1) * 64;
    const ushort* Xbase = X + (size_t)(m0 + r0) * HH + c * 8;
    const ushort* Wbase = W + (size_t)(n0 + r0) * HH + c * 8;
    f32x4 acc[4][4] = {};
#define LOADSET(x0_,x1_,x2_,x3_,w0_,w1_,w2_,w3_,KOFF)                          \
    x0_ = *(const uint4*)(Xbase + (KOFF));                                     \
    x1_ = *(const uint4*)(Xbase + (size_t)32 * HH + (KOFF));                   \
    x2_ = *(const uint4*)(Xbase + (size_t)64 * HH + (KOFF));                   \
    x3_ = *(const uint4*)(Xbase + (size_t)96 * HH + (KOFF));                   \
    w0_ = *(const uint4*)(Wbase + (KOFF));                                     \
    w1_ = *(const uint4*)(Wbase + (size_t)32 * HH + (KOFF));                   \
    w2_ = *(const uint4*)(Wbase + (size_t)64 * HH + (KOFF));                   \
    w3_ = *(const uint4*)(Wbase + (size_t)96 * HH + (KOFF));
#define STORESET(x0_,x1_,x2_,x3_,w0_,w1_,w2_,w3_)                              \
    *(uint4*)&As[r0 * 64 + ssw] = x0_;                                         \
    *(uint4*)&As[(r0 + 32) * 64 + ssw] = x1_;                                  \
    *(uint4*)&As[(r0 + 64) * 64 + ssw] = x2_;                                  \
    *(uint4*)&As[(r0 + 96) * 64 + ssw] = x3_;                                  \
    *(uint4*)&Bs[r0 * 64 + ssw] = w0_;                                         \
    *(uint4*)&Bs[(r0 + 32) * 64 + ssw] = w1_;                                  \
    *(uint4*)&Bs[(r0 + 64) * 64 + ssw] = w2_;                                  \
    *(uint4*)&Bs[(r0 + 96) * 64 + ssw] = w3_;
#define DOMFMA()                                                               \
    { bf16x8 af[4][2], bfr[4][2];                                              \
      _Pragma("unroll")                                                        \
      for (int mt = 0; mt < 4; ++mt)                                           \
        _Pragma("unroll")                                                      \
        for (int kt = 0; kt < 2; ++kt) {                                       \
          int row = wm + mt * 16 + lm, ch = lg + kt * 4;                       \
          af[mt][kt] = *(bf16x8*)&As[row * 64 + ((ch ^ (row & 7)) * 8)];       \
        }                                                                      \
      _Pragma("unroll")                                                        \
      for (int nt = 0; nt < 4; ++nt)                                           \
        _Pragma("unroll")                                                      \
        for (int kt = 0; kt < 2; ++kt) {                                       \
          int row = wn + nt * 16 + lm, ch = lg + kt * 4;                       \
          bfr[nt][kt] = *(bf16x8*)&Bs[row * 64 + ((ch ^ (row & 7)) * 8)];      \
        }                                                                      \
      _Pragma("unroll")                                                        \
      for (int mt = 0; mt < 4; ++mt)                                           \
        _Pragma("unroll")                                                      \
        for (int nt = 0; nt < 4; ++nt)                                         \
          _Pragma("unroll")                                                    \
          for (int kt = 0; kt < 2; ++kt)                                       \
            acc[mt][nt] = __builtin_amdgcn_mfma_f32_16x16x32_bf16(             \
                af[mt][kt], bfr[nt][kt], acc[mt][nt], 0, 0, 0); }
    uint4 xA0, xA1, xA2, xA3, wA0, wA1, wA2, wA3;
    uint4 xB0, xB1, xB2, xB3, wB0, wB1, wB2, wB3;
    LOADSET(xA0, xA1, xA2, xA3, wA0, wA1, wA2, wA3, 0)
    LOADSET(xB0, xB1, xB2, xB3, wB0, wB1, wB2, wB3, 64)
    for (int k0 = 0; k0 < HH; k0 += 128) {
      if (k0) __syncthreads();
      STORESET(xA0, xA1, xA2, xA3, wA0, wA1, wA2, wA3)
      __syncthreads();
      if (k0 + 128 < HH) { LOADSET(xA0, xA1, xA2, xA3, wA0, wA1, wA2, wA3, k0 + 128) }
      DOMFMA()
      __syncthreads();
      STORESET(xB0, xB1, xB2, xB3, wB0, wB1, wB2, wB3)
      __syncthreads();
      if (k0 + 192 < HH) { LOADSET(xB0, xB1, xB2, xB3, wB0, wB1, wB2, wB3, k0 + 192) }
      DOMFMA()
    }
#undef LOADSET
#undef STORESET
#undef DOMFMA
    if (z == 2) {
#pragma unroll
      for (int nt = 0; nt < 4; ++nt) {
        int col = n0 + wn + nt * 16 + lm;
        int hh = col >> 6, dd = col & 63;
        float bcol = bias[col];
#pragma unroll
        for (int mt = 0; mt < 4; ++mt) {
          int row0 = m0 + wm + mt * 16 + lg * 4;
          int bb2 = row0 >> 10, nr = row0 & (NN - 1);
          ushort4 o;
          o.x = f2bf(acc[mt][nt][0] + bcol);
          o.y = f2bf(acc[mt][nt][1] + bcol);
          o.z = f2bf(acc[mt][nt][2] + bcol);
          o.w = f2bf(acc[mt][nt][3] + bcol);
          *(ushort4*)(C + ((size_t)(bb2 * NHD + hh) * ASZ + dd) * NN + nr) = o;
        }
      }
    } else {
#pragma unroll
      for (int nt = 0; nt < 4; ++nt) {
        int col = n0 + wn + nt * 16 + lm;
        float bcol = bias[col];
#pragma unroll
        for (int mt = 0; mt < 4; ++mt)
#pragma unroll
          for (int rr = 0; rr < 4; ++rr) {
            int row = m0 + wm + mt * 16 + lg * 4 + rr;
            C[(size_t)row * HH + col] = f2bf((acc[mt][nt][rr] + bcol) * alpha);
          }
      }
    }
  } else {
    // ---------------- score GEMM path (1-deep prefetch, unchanged) ----------------
    const int bid2 = bid - GEMM_BLKS;
    const int b = bid2 / 72;
    const int rem = bid2 % 72;
    const int j0 = (rem / 12) * 64;
    const int n0g = (rem % 12) * 128;
    const int cnt = pcnt[b];
    if (j0 >= cnt) return;
    const bool symh = n0g >= HH;
    const int n0 = symh ? n0g - HH : n0g;
    const ushort* W = symh ? Wsym : Wvar;
    const float* bias = symh ? bsym : bvar;
    ushort* As = Sm;           // 64*64
    ushort* Bs = Sm + 4096;    // 128*64
    const int wm = (w >> 1) * 32, wn = (w & 1) * 64;
    if (t < 64) {
      int j = j0 + t;
      pl[t] = (j < cnt) ? plist[b * NN + j] : 2;
      red[t] = 0.f;
    }
    __syncthreads();
    const ushort* ap0; const ushort* ap1;
    if (symh) {
      const ushort* xbb = X + (size_t)b * NN * HH;
      ap0 = xbb + (size_t)pl[r0] * HH + c * 8;
      ap1 = xbb + (size_t)pl[r0 + 32] * HH + c * 8;
    } else {
      const ushort* vrb = vrows + ((size_t)b * PRMAX + j0) * HH;
      ap0 = vrb + (size_t)r0 * HH + c * 8;
      ap1 = vrb + (size_t)(r0 + 32) * HH + c * 8;
    }
    const ushort* bp = W + (size_t)(n0 + r0) * HH + c * 8;
    uint4 ar0 = *(const uint4*)ap0;
    uint4 ar1 = *(const uint4*)ap1;
    uint4 br0 = *(const uint4*)bp;
    uint4 br1 = *(const uint4*)(bp + (size_t)32 * HH);
    uint4 br2 = *(const uint4*)(bp + (size_t)64 * HH);
    uint4 br3 = *(const uint4*)(bp + (size_t)96 * HH);
    f32x4 acc[2][4] = {};
    for (int k0 = 0; k0 < HH; k0 += 64) {
      if (k0) __syncthreads();
      *(uint4*)&As[r0 * 64 + ssw] = ar0;
      *(uint4*)&As[(r0 + 32) * 64 + ssw] = ar1;
      *(uint4*)&Bs[r0 * 64 + ssw] = br0;
      *(uint4*)&Bs[(r0 + 32) * 64 + ssw] = br1;
      *(uint4*)&Bs[(r0 + 64) * 64 + ssw] = br2;
      *(uint4*)&Bs[(r0 + 96) * 64 + ssw] = br3;
      __syncthreads();
      if (k0 + 64 < HH) {
        ap0 += 64; ap1 += 64; bp += 64;
        ar0 = *(const uint4*)ap0;
        ar1 = *(const uint4*)ap1;
        br0 = *(const uint4*)bp;
        br1 = *(const uint4*)(bp + (size_t)32 * HH);
        br2 = *(const uint4*)(bp + (size_t)64 * HH);
        br3 = *(const uint4*)(bp + (size_t)96 * HH);
      }
      bf16x8 af[2][2], bfr[4][2];
#pragma unroll
      for (int mt = 0; mt < 2; ++mt)
#pragma unroll
        for (int kt = 0; kt < 2; ++kt) {
          int row = wm + mt * 16 + lm, ch = lg + kt * 4;
          af[mt][kt] = *(bf16x8*)&As[row * 64 + ((ch ^ (row & 7)) * 8)];
        }
#pragma unroll
      for (int nt = 0; nt < 4; ++nt)
#pragma unroll
        for (int kt = 0; kt < 2; ++kt) {
          int row = wn + nt * 16 + lm, ch = lg + kt * 4;
          bfr[nt][kt] = *(bf16x8*)&Bs[row * 64 + ((ch ^ (row & 7)) * 8)];
        }
#pragma unroll
      for (int mt = 0; mt < 2; ++mt)
#pragma unroll
        for (int nt = 0; nt < 4; ++nt)
#pragma unroll
          for (int kt = 0; kt < 2; ++kt)
            acc[mt][nt] = __builtin_amdgcn_mfma_f32_16x16x32_bf16(af[mt][kt], bfr[nt][kt], acc[mt][nt], 0, 0, 0);
    }
    float bcol[4], wcol[4];
#pragma unroll
    for (int nt = 0; nt < 4; ++nt) {
      int cl = wn + nt * 16 + lm;
      bcol[nt] = bias[n0 + cl];
      wcol[nt] = wscore[n0g + cl];
    }
#pragma unroll
    for (int mt = 0; mt < 2; ++mt)
#pragma unroll
      for (int rr = 0; rr < 4; ++rr) {
        float p = 0.f;
#pragma unroll
        for (int nt = 0; nt < 4; ++nt)
          p += fast_tanh(acc[mt][nt][rr] + bcol[nt]) * wcol[nt];
        p += __shfl_xor(p, 1); p += __shfl_xor(p, 2);
        p += __shfl_xor(p, 4); p += __shfl_xor(p, 8);
        if (lm == 0) atomicAdd(&red[wm + mt * 16 + lg * 4 + rr], p);
      }
    __syncthreads();
    if (t < 64) {
      int j2 = j0 + t;
      if (j2 < cnt) atomicAdd(&s_raw[b * NN + pl[t]], red[t]);
    }
  }
}

// ============ K_attn2: swapped-QK^T no-max flash attention ============
// 4 waves x 16 q-rows (64 q/block); KVBLK=64; exp2 domain, no max subtraction.
__global__ __launch_bounds__(256, 4) void k_attn2(
    const ushort* __restrict__ qg, const ushort* __restrict__ kg, const ushort* __restrict__ vtg,
    const float4* __restrict__ bias4, const int* __restrict__ pp, float* __restrict__ zz) {
  __shared__ ushort Ks[64 * 64];
  __shared__ ushort Vts[64 * 64];
  const int rb = blockIdx.y, h = blockIdx.x >> 3, b = blockIdx.x & 7;
  const int n0 = rb * 64;
  const int t = threadIdx.x, w = t >> 6, lane = t & 63, lg = lane >> 4, lm = lane & 15;
  const int qbase = n0 + w * 16;
  const ushort* qrow = qg + (size_t)(b * NN + qbase + lm) * HH + h * ASZ;
  bf16x8 qf[2];
  qf[0] = *(const bf16x8*)(qrow + lg * 8);
  qf[1] = *(const bf16x8*)(qrow + lg * 8 + 32);
  float4 bz = bias4[b * NN + qbase + lm];
  const int cwq = __float_as_int(bz.x);
  f32x4 suml = {0.f, 0.f, 0.f, 0.f};   // per-lane partial l (reduced in epilogue)
  f32x4 y[4] = {};
  const ushort* kb = kg + (size_t)(b * NN) * HH + h * ASZ;
  const ushort* vtb = vtg + (size_t)(b * NHD + h) * ASZ * NN;
  const int srow = t >> 3, sc = t & 7;
  const int arow = (srow & 35) | ((srow & 4) << 2) | ((srow & 24) >> 1);  // 6-bit perm
  const int kssw = (sc ^ (arow & 7)) * 8;
  const int vssw = (sc ^ (srow & 7)) * 8;
  const ushort* kptr = kb + (size_t)srow * HH + sc * 8;
  const ushort* vptr = vtb + (size_t)srow * NN + sc * 8;
  uint4 ka = *(const uint4*)kptr;
  uint4 kc = *(const uint4*)(kptr + (size_t)32 * HH);
  uint4 va = *(const uint4*)vptr;
  uint4 vb2 = *(const uint4*)(vptr + (size_t)32 * NN);
  for (int tile = 0; tile < 16; ++tile) {
    const int c0 = tile * 64;
    *(uint4*)&Ks[arow * 64 + kssw] = ka;
    *(uint4*)&Ks[(arow + 32) * 64 + kssw] = kc;
    *(uint4*)&Vts[srow * 64 + vssw] = va;
    *(uint4*)&Vts[(srow + 32) * 64 + vssw] = vb2;
    __syncthreads();
    if (tile < 15) {   // prefetch next tile into registers
      kptr += (size_t)64 * HH; vptr += 64;
      ka = *(const uint4*)kptr;
      kc = *(const uint4*)(kptr + (size_t)32 * HH);
      va = *(const uint4*)vptr;
      vb2 = *(const uint4*)(vptr + (size_t)32 * NN);
    }
    f32x4 s[4] = {};
    __builtin_amdgcn_s_setprio(1);
#pragma unroll
    for (int nt = 0; nt < 4; ++nt) {
      int krow = lm + nt * 16, sw = krow & 7;
#pragma unroll
      for (int kt = 0; kt < 2; ++kt) {
        bf16x8 kf = *(bf16x8*)&Ks[krow * 64 + (((lg + kt * 4) ^ sw) * 8)];
        s[nt] = __builtin_amdgcn_mfma_f32_16x16x32_bf16(kf, qf[kt], s[nt], 0, 0, 0);
      }
    }
    __builtin_amdgcn_s_setprio(0);
    // sparse bias: token of s[nt][r] = c0 + (nt>>1)*32 + lg*8 + (nt&1)*4 + r
    if (c0 <= qbase + 17 && qbase <= c0 + 65) {
#pragma unroll
      for (int nt = 0; nt < 4; ++nt) {
        int kb2 = c0 + (nt >> 1) * 32 + lg * 8 + (nt & 1) * 4;
#pragma unroll
        for (int r = 0; r < 4; ++r) {
          int dd = kb2 + r - cwq;
          if (dd >= 0 && dd < 3) s[nt][r] += (dd == 0) ? bz.y : (dd == 1 ? bz.z : bz.w);
        }
      }
    }
    // no-max exp: p = 2^s directly (bounded logits); accumulate per-lane l
#pragma unroll
    for (int nt = 0; nt < 4; ++nt)
#pragma unroll
      for (int e = 0; e < 4; ++e) {
        float p = EXP2F(s[nt][e]);
        s[nt][e] = p;
        suml[e] += p;
      }
    // pack P into PV A-frags via v_perm (register-local)
    union { unsigned u[4]; bf16x8 v; } pk[2];
#pragma unroll
    for (int kt = 0; kt < 2; ++kt) {
      pk[kt].u[0] = packbf2(s[2 * kt][0], s[2 * kt][1]);
      pk[kt].u[1] = packbf2(s[2 * kt][2], s[2 * kt][3]);
      pk[kt].u[2] = packbf2(s[2 * kt + 1][0], s[2 * kt + 1][1]);
      pk[kt].u[3] = packbf2(s[2 * kt + 1][2], s[2 * kt + 1][3]);
    }
    __builtin_amdgcn_s_setprio(1);
#pragma unroll
    for (int nt = 0; nt < 4; ++nt) {
      int vrow = lm + nt * 16, sw = vrow & 7;
#pragma unroll
      for (int kt = 0; kt < 2; ++kt) {
        bf16x8 vf = *(bf16x8*)&Vts[vrow * 64 + (((lg + kt * 4) ^ sw) * 8)];
        y[nt] = __builtin_amdgcn_mfma_f32_16x16x32_bf16(pk[kt].v, vf, y[nt], 0, 0, 0);
      }
    }
    __builtin_amdgcn_s_setprio(0);
    __syncthreads();
  }
  // epilogue: reduce l once, then weighted row-sums into z1/z2
  float ts = (suml[0] + suml[1]) + (suml[2] + suml[3]);
  ts += __shfl_xor(ts, 16);
  ts += __shfl_xor(ts, 32);
  float invl = 1.f / ts;                 // l for q = qbase+lm
  float invq[4], c1v[4], c2v[4];
#pragma unroll
  for (int r = 0; r < 4; ++r) {
    invq[r] = __shfl(invl, lg * 4 + r);
    coefs(pp + b * NN, qbase + lg * 4 + r, c1v[r], c2v[r]);
  }
  float a1[4], a2[4];
#pragma unroll
  for (int nt = 0; nt < 4; ++nt) {
    float u1 = 0.f, u2 = 0.f;
#pragma unroll
    for (int r = 0; r < 4; ++r) {
      float yv = y[nt][r] * invq[r];
      u1 += c1v[r] * yv;
      u2 += c2v[r] * yv;
    }
    u1 += __shfl_xor(u1, 16); u1 += __shfl_xor(u1, 32);
    u2 += __shfl_xor(u2, 16); u2 += __shfl_xor(u2, 32);
    a1[nt] = u1; a2[nt] = u2;
  }
  if (lg == 0) {
#pragma unroll
    for (int nt = 0; nt < 4; ++nt) {
      atomicAdd(&zz[b * HH + h * ASZ + nt * 16 + lm], a1[nt]);
      atomicAdd(&zz[BB * HH + b * HH + h * ASZ + nt * 16 + lm], a2[nt]);
    }
  }
}

// ============ F1: t_s = W_o @ (z_s / sumw) + b_o ============
__global__ void k_f1(const float* __restrict__ Wo, const float* __restrict__ bo,
                     const float* __restrict__ zz, const float* __restrict__ sumw,
                     float* __restrict__ tvec) {
  int b = blockIdx.y;
  int w = threadIdx.x >> 6, lane = threadIdx.x & 63;
  float inv = 1.f / sumw[b];
  const float* z1 = zz + b * HH;
  const float* z2 = zz + BB * HH + b * HH;
  float zr1[12], zr2[12];
#pragma unroll
  for (int m = 0; m < 12; ++m) { zr1[m] = z1[lane + 64 * m] * inv; zr2[m] = z2[lane + 64 * m] * inv; }
  for (int j = 0; j < 8; ++j) {
    int o = blockIdx.x * 32 + w * 8 + j;
    const float* wrow = Wo + (size_t)o * HH;
    float a1 = 0.f, a2 = 0.f;
#pragma unroll
    for (int m = 0; m < 12; ++m) { float wv = wrow[lane + 64 * m]; a1 += wv * zr1[m]; a2 += wv * zr2[m]; }
    for (int mask = 32; mask; mask >>= 1) { a1 += __shfl_xor(a1, mask); a2 += __shfl_xor(a2, mask); }
    if (lane == 0) { tvec[b * HH + o] = a1 + bo[o]; tvec[BB * HH + b * HH + o] = a2 + bo[o]; }
  }
}

// ============ F2: pm = WL @ t1 + WR @ t2 + b_atom ============
__global__ void k_f2(const float* __restrict__ Wa, const float* __restrict__ ba,
                     const float* __restrict__ tvec, float* __restrict__ pm) {
  int b = blockIdx.y;
  int w = threadIdx.x >> 6, lane = threadIdx.x & 63;
  const float* t1 = tvec + b * HH;
  const float* t2 = tvec + BB * HH + b * HH;
  float r1[12], r2[12];
#pragma unroll
  for (int m = 0; m < 12; ++m) { r1[m] = t1[lane + 64 * m]; r2[m] = t2[lane + 64 * m]; }
  for (int j = 0; j < 8; ++j) {
    int o = blockIdx.x * 32 + w * 8 + j;
    const float* wrow = Wa + (size_t)o * (2 * HH);
    float a = 0.f;
#pragma unroll
    for (int m = 0; m < 12; ++m) a += wrow[lane + 64 * m] * r1[m];
#pragma unroll
    for (int m = 0; m < 12; ++m) a += wrow[HH + lane + 64 * m] * r2[m];
    for (int mask = 32; mask; mask >>= 1) a += __shfl_xor(a, mask);
    if (lane == 0) pm[b * HH + o] = a + ba[o];
  }
}

// ============ F3: broadcast pm to (B,N,H) ============
__global__ void k_bcast(const float* __restrict__ pm, float* __restrict__ out) {
  size_t g = (size_t)blockIdx.x * 256 + threadIdx.x;
  int b = (int)(g / ((size_t)NN * HH / 4));
  int hh4 = (int)(g % (HH / 4));
  float4 val = *(const float4*)(pm + b * HH + hh4 * 4);
  *(float4*)(out + g * 4) = val;
}

// ================= launcher =================
extern "C" void kernel_launch(void* const* d_in, const int* in_sizes, int n_in,
                              void* d_out, int out_size, void* d_ws, size_t ws_size,
                              hipStream_t stream) {
  (void)in_sizes; (void)n_in; (void)out_size; (void)ws_size;
  const float* x       = (const float*)d_in[0];
  const float* W_var   = (const float*)d_in[3];
  const float* b_var   = (const float*)d_in[4];
  const float* W_sym   = (const float*)d_in[5];
  const float* b_sym   = (const float*)d_in[6];
  const float* W_score = (const float*)d_in[7];
  const float* b_score = (const float*)d_in[8];
  const float* W_cross = (const float*)d_in[9];
  const float* b_cross = (const float*)d_in[10];
  const float* W_atom  = (const float*)d_in[11];
  const float* b_atom  = (const float*)d_in[12];
  const float* W_q     = (const float*)d_in[13];
  const float* b_q     = (const float*)d_in[14];
  const float* W_k     = (const float*)d_in[15];
  const float* b_k     = (const float*)d_in[16];
  const float* W_v     = (const float*)d_in[17];
  const float* b_v     = (const float*)d_in[18];
  const float* W_o     = (const float*)d_in[19];
  const float* b_o     = (const float*)d_in[20];
  const int*   pp      = (const int*)d_in[21];
  const int*   occ     = (const int*)d_in[24];
  float* out = (float*)d_out;
  char* wsb = (char*)d_ws;
  ushort* qb  = (ushort*)(wsb + OFFB_QB);
  ushort* kbf = (ushort*)(wsb + OFFB_KB);
  ushort* vtb = (ushort*)(wsb + OFFB_VB);
  ushort* xb  = (ushort*)(wsb + OFFB_XB);
  ushort* wqb = (ushort*)(wsb + OFFB_WQB);
  ushort* wkb = (ushort*)(wsb + OFFB_WKB);
  ushort* wvb = (ushort*)(wsb + OFFB_WVB);
  ushort* wvar = (ushort*)(wsb + OFFB_WVAR);
  ushort* wsym = (ushort*)(wsb + OFFB_WSYM);
  ushort* vrows = (ushort*)(wsb + OFFB_VROWS);
  float* sraw = (float*)(wsb + OFFB_SRAW);
  float* diag = (float*)(wsb + OFFB_DIAG);
  float4* bias4 = (float4*)(wsb + OFFB_BIAS4);
  int* plist = (int*)(wsb + OFFB_PLIST);
  int* pcnt  = (int*)(wsb + OFFB_PCNT);
  float* sumw = (float*)(wsb + OFFB_SUMW);
  float* zz   = (float*)(wsb + OFFB_ZZ);
  float* tv   = (float*)(wsb + OFFB_TV);
  float* pm   = (float*)(wsb + OFFB_PM);

  k_pred<<<BB, 64, 0, stream>>>(pp, plist, pcnt, sumw, sraw, diag, zz);
  // f32->bf16 (x + 5 weights) fused with occurrence-pair scores
  k_cvtall<<<NCVT + BB * MM / 4, 256, 0, stream>>>(
      x, W_q, W_k, W_v, W_var, W_sym, xb, wqb, wkb, wvb, wvar, wsym,
      occ, W_cross, b_cross, diag);
  // gather var_in rows (bf16, compact)
  k_gather<<<dim3(PRMAX / 4, BB), 256, 0, stream>>>(xb, pp, plist, pcnt, vrows);
  // fused QKV GEMM + score GEMM (independent, co-scheduled; 2-deep prefetch)
  k_mats<<<MATS_BLKS, 256, 0, stream>>>(
      xb, vrows, plist, pcnt, wvar, wsym, b_var, b_sym, W_score, sraw,
      wqb, wkb, wvb, b_q, b_k, b_v, qb, kbf, vtb);
  k_bias<<<BB * NN / 256, 256, 0, stream>>>(pp, sraw, diag, b_score, bias4);
  // MFMA flash attention (64 q-rows/block, 4 waves, no-max exp2 softmax)
  k_attn2<<<dim3(NHD * BB, NN / 64), 256, 0, stream>>>(qb, kbf, vtb, bias4, pp, zz);
  k_f1<<<dim3(24, BB), 256, 0, stream>>>(W_o, b_o, zz, sumw, tv);
  k_f2<<<dim3(24, BB), 256, 0, stream>>>(W_atom, b_atom, tv, pm);
  k_bcast<<<BB * NN * HH / 1024, 256, 0, stream>>>(pm, out);
}

// Round 19
// 148.839 us; speedup vs baseline: 1.0066x; 1.0066x over previous
//
#include <hip/hip_runtime.h>
#include <hip/hip_bf16.h>

// ================= problem constants =================
#define BB 8
#define NN 1024
#define HH 768
#define NHD 12
#define ASZ 64
#define MM 256
#define QSCALE 0.125f   // AS^-0.5
#define NSLOPE 0.02f
#define LOG2E 1.44269504f
#define PRMAX 384       // padded predicate rows per batch

typedef __attribute__((ext_vector_type(8))) short bf16x8;
typedef __attribute__((ext_vector_type(4))) float f32x4;

#define EXP2F(x) __builtin_amdgcn_exp2f(x)
#define RCPF(x)  __builtin_amdgcn_rcpf(x)

// ============ workspace layout (byte offsets, all 16B-aligned) ============
#define OFFB_QB    ((size_t)0)            // 8*1024*768 bf16
#define OFFB_KB    ((size_t)12582912)
#define OFFB_VB    ((size_t)25165824)     // V^T: [b][h][d][n] bf16
#define OFFB_XB    ((size_t)37748736)     // x in bf16
#define OFFB_WQB   ((size_t)50331648)     // 768*768 bf16
#define OFFB_WKB   ((size_t)51511296)
#define OFFB_WVB   ((size_t)52690944)
#define OFFB_WVAR  ((size_t)53870592)     // W_var bf16
#define OFFB_WSYM  ((size_t)55050240)     // W_sym bf16
#define OFFB_SRAW  ((size_t)56229888)     // 8192 f32
#define OFFB_DIAG  ((size_t)56262656)     // 8192 f32
#define OFFB_BIAS4 ((size_t)56295424)     // 8192 float4
#define OFFB_PLIST ((size_t)56426496)     // 8192 i32
#define OFFB_PCNT  ((size_t)56459264)
#define OFFB_SUMW  ((size_t)56459296)
#define OFFB_ZZ    ((size_t)56459328)     // 2*8*768 f32
#define OFFB_TV    ((size_t)56508480)
#define OFFB_PM    ((size_t)56557632)
#define OFFB_VROWS ((size_t)56582208)     // 8*384*768 bf16 gathered var rows

__device__ __forceinline__ float lrelu(float v) { return v >= 0.f ? v : NSLOPE * v; }

__device__ __forceinline__ ushort f2bf(float f) {  // round-half-up f32->bf16 (2 ops)
  return (ushort)((__float_as_uint(f) + 0x8000u) >> 16);
}
__device__ __forceinline__ float bf2f(ushort u) {
  union { unsigned u; float f; } v; v.u = (unsigned)u << 16;
  return v.f;
}
__device__ __forceinline__ unsigned packbf2(float lo, float hi) {  // (bf(hi)<<16)|bf(lo)
  unsigned a = __float_as_uint(hi) + 0x8000u;
  unsigned b = __float_as_uint(lo) + 0x8000u;
  return __builtin_amdgcn_perm(a, b, 0x07060302u);
}
__device__ __forceinline__ float fast_tanh(float x) {  // exp2-domain, saturates to +-1
  float e = EXP2F(x * (2.f * LOG2E));
  return 1.f - 2.f * RCPF(e + 1.f);
}

// weights for the final weighted row-sums of y (derived from pm algebra).
__device__ __forceinline__ void coefs(const int* ppb, int j, float& c1, float& c2) {
  auto pred = [&](int tt) { return tt >= 0 && tt < NN && ppb[tt] == 1; };
  auto single = [&](int tt) { return tt == 0 || (tt >= 2 && ppb[tt - 2] == 1); };
  auto wgt = [&](int tt) {
    if (!pred(tt)) return 0.f;
    bool tri = (tt >= 1) && (tt <= 1 || !single(tt));
    return tri ? 3.f : 2.f;
  };
  float a = 0.f;
  if (pred(j + 1)) a += wgt(j + 1) * (single(j + 1) ? 0.f : 0.5f);
  if (j >= 1 && pred(j - 1)) a += wgt(j - 1) * (single(j - 1) ? 1.f : 0.5f);
  c1 = a;
  c2 = wgt(j);
}

// ============ K_pred: compact predicate list + sum of weights + ws zeroing ============
__global__ void k_pred(const int* __restrict__ pp, int* __restrict__ plist,
                       int* __restrict__ pcnt, float* __restrict__ sumw,
                       float* __restrict__ sraw, float* __restrict__ diag,
                       float* __restrict__ zz) {
  int b = blockIdx.x;
  int lane = threadIdx.x;  // blockDim 64
  const int* ppb = pp + b * NN;
  int base = 0;
  float wacc = 0.f;
  for (int c = 0; c < NN; c += 64) {
    int i = c + lane;
    bool isp = ppb[i] == 1;
    unsigned long long mask = __ballot(isp);
    if (isp) {
      int pos = base + __popcll(mask & ((1ull << lane) - 1ull));
      plist[b * NN + pos] = i;
      bool sing = (i == 0) || (i >= 2 && ppb[i - 2] == 1);
      bool tri = (i >= 1) && (i <= 1 || !sing);
      wacc += tri ? 3.f : 2.f;
    }
    base += __popcll(mask);
  }
  for (int off = 32; off; off >>= 1) wacc += __shfl_xor(wacc, off);
  if (lane == 0) { pcnt[b] = base; sumw[b] = wacc; }
  for (int c = lane; c < NN; c += 64) { sraw[b * NN + c] = 0.f; diag[b * NN + c] = 0.f; }
  for (int c = lane; c < HH; c += 64) {
    zz[b * HH + c] = 0.f;
    zz[BB * HH + b * HH + c] = 0.f;
  }
}

// ============ K_cvtall: x + 5 weights f32->bf16, plus cross scores ============
#define NXQ (BB * NN * HH / 4)      // 1572864
#define WQ  (HH * HH / 4)           // 147456
#define NCVT ((NXQ + 5 * WQ) / 256) // 9024
__global__ void k_cvtall(const float* __restrict__ x,
                         const float* __restrict__ s1, const float* __restrict__ s2,
                         const float* __restrict__ s3, const float* __restrict__ s4,
                         const float* __restrict__ s5,
                         ushort* __restrict__ dx,
                         ushort* __restrict__ d1, ushort* __restrict__ d2,
                         ushort* __restrict__ d3, ushort* __restrict__ d4,
                         ushort* __restrict__ d5,
                         const int* __restrict__ occ, const float* __restrict__ Wc,
                         const float* __restrict__ bc, float* __restrict__ diag) {
  if (blockIdx.x < NCVT) {
    int idx = blockIdx.x * 256 + threadIdx.x;
    const float* src; ushort* dst; int off;
    if (idx < NXQ) { src = x; dst = dx; off = idx; }
    else {
      int r = idx - NXQ;
      int z = r / WQ;
      off = r - z * WQ;
      src = z == 0 ? s1 : z == 1 ? s2 : z == 2 ? s3 : z == 3 ? s4 : s5;
      dst = z == 0 ? d1 : z == 1 ? d2 : z == 2 ? d3 : z == 3 ? d4 : d5;
    }
    float4 v = ((const float4*)src)[off];
    ushort4 o;
    o.x = f2bf(v.x); o.y = f2bf(v.y); o.z = f2bf(v.z); o.w = f2bf(v.w);
    ((ushort4*)dst)[off] = o;
  } else {
    int g = (blockIdx.x - NCVT) * 4 + (threadIdx.x >> 6);
    int lane = threadIdx.x & 63;
    int b = g >> 8, m = g & (MM - 1);
    int o0 = occ[(b * MM + m) * 2 + 0];
    int o1 = occ[(b * MM + m) * 2 + 1];
    const float* x0 = x + (size_t)(b * NN + o0) * HH;
    const float* x1 = x + (size_t)(b * NN + o1) * HH;
    float acc = 0.f;
    for (int d = lane; d < HH; d += 64) acc += 0.5f * (x0[d] + x1[d]) * Wc[d];
    for (int off = 32; off; off >>= 1) acc += __shfl_xor(acc, off);
    if (lane == 0) {
      float sc = lrelu(acc + bc[0]);
      float sq = sc * sc;
      diag[b * NN + o0] = sq;
      diag[b * NN + o1] = sq;
    }
  }
}

// ============ K_gather: compact var_in rows (bf16) for the score GEMM ============
__global__ void k_gather(const ushort* __restrict__ xb, const int* __restrict__ pp,
                         const int* __restrict__ plist, const int* __restrict__ pcnt,
                         ushort* __restrict__ vrows) {
  int b = blockIdx.y;
  int j = blockIdx.x * 4 + (threadIdx.x >> 6);
  int lane = threadIdx.x & 63;
  if (j >= pcnt[b]) return;
  int i = plist[b * NN + j];
  bool sing = (i == 0) || (i >= 2 && pp[b * NN + i - 2] == 1);
  float wa = sing ? 0.f : 0.5f, wb = sing ? 1.f : 0.5f;
  const ushort* rp = xb + (size_t)(b * NN + ((i - 1) & (NN - 1))) * HH;
  const ushort* rn = xb + (size_t)(b * NN + ((i + 1) & (NN - 1))) * HH;
  ushort* dst = vrows + ((size_t)b * PRMAX + j) * HH;
#pragma unroll
  for (int it = 0; it < 3; ++it) {
    int d4 = lane + it * 64;
    ushort4 p4 = ((const ushort4*)rp)[d4];
    ushort4 n4 = ((const ushort4*)rn)[d4];
    ushort4 o;
    o.x = f2bf(wa * bf2f(p4.x) + wb * bf2f(n4.x));
    o.y = f2bf(wa * bf2f(p4.y) + wb * bf2f(n4.y));
    o.z = f2bf(wa * bf2f(p4.z) + wb * bf2f(n4.z));
    o.w = f2bf(wa * bf2f(p4.w) + wb * bf2f(n4.w));
    ((ushort4*)dst)[d4] = o;
  }
}

// ============ K_bias: per-row sparse bias window (log2e-scaled for exp2 softmax) ============
__global__ void k_bias(const int* __restrict__ pp, const float* __restrict__ s_raw,
                       const float* __restrict__ diag, const float* __restrict__ b_score,
                       float4* __restrict__ bias4) {
  int g = blockIdx.x * 256 + threadIdx.x;
  int b = g >> 10, r = g & (NN - 1);
  const int* ppb = pp + b * NN;
  int i = -1;
  if (ppb[r] == 1) i = r;
  else if (r + 1 < NN && ppb[r + 1] == 1) i = r + 1;
  else if (r >= 1 && ppb[r - 1] == 1) i = r - 1;
  float v0 = 0.f, v1 = 0.f, v2 = 0.f; int cw = r;
  if (i >= 1 && i + 1 < NN) {
    float s = lrelu(s_raw[b * NN + i] + b_score[0]);
    float s2 = s * s;
    cw = i - 1;
    if (i == r) { v0 = 0.2f * s; v1 = 1.6f * s2; v2 = 0.2f * s; }
    else       { v0 = 0.8f * s2; v1 = 0.2f * s; v2 = 0.8f * s2; }
  }
  int slot = r - cw;
  float d = diag[g];
  if (slot == 0) v0 += d; else if (slot == 1) v1 += d; else v2 += d;
  bias4[g] = make_float4(__int_as_float(cw), v0 * LOG2E, v1 * LOG2E, v2 * LOG2E);
}

// ============ K_mats: fused {QKV GEMM (1152 blocks)} + {score GEMM (576 blocks)} ============
#define GEMM_BLKS 1152
#define MATS_BLKS 1728
__global__ __launch_bounds__(256, 2) void k_mats(
    const ushort* __restrict__ X, const ushort* __restrict__ vrows,
    const int* __restrict__ plist, const int* __restrict__ pcnt,
    const ushort* __restrict__ Wvar, const ushort* __restrict__ Wsym,
    const float* __restrict__ bvar, const float* __restrict__ bsym,
    const float* __restrict__ wscore, float* __restrict__ s_raw,
    const ushort* __restrict__ W0, const ushort* __restrict__ W1, const ushort* __restrict__ W2,
    const float* __restrict__ b0, const float* __restrict__ b1, const float* __restrict__ b2,
    ushort* __restrict__ C0, ushort* __restrict__ C1, ushort* __restrict__ C2) {
  __shared__ ushort Sm[16384];   // 32 KB carve
  __shared__ int pl[64];
  __shared__ float red[64];
  const int bid = blockIdx.x;    // natural order (XCD swizzle measured harmful)
  const int t = threadIdx.x;
  const int w = t >> 6, lane = t & 63, lg = lane >> 4, lm = lane & 15;
  const int r0 = t >> 3, c = t & 7;
  const int ssw = (c ^ (r0 & 7)) * 8;
  if (bid < GEMM_BLKS) {
    // ---------------- QKV GEMM path ----------------
    const int z = bid / 384;
    const int r = bid % 384;
    const int m0 = (r & 63) * 128, n0 = (r >> 6) * 128;
    const ushort* W = z == 0 ? W0 : (z == 1 ? W1 : W2);
    const float* bias = z == 0 ? b0 : (z == 1 ? b1 : b2);
    ushort* C = z == 0 ? C0 : (z == 1 ? C1 : C2);
    const float alpha = z == 0 ? QSCALE * LOG2E : 1.f;
    ushort* As = Sm;
    ushort* Bs = Sm + 8192;
    const int wm = (w >> 1) * 64, wn = (w & 1) * 64;
    const ushort* Xp = X + (size_t)(m0 + r0) * HH + c * 8;
    const ushort* Wp = W + (size_t)(n0 + r0) * HH + c * 8;
    uint4 xa0 = *(const uint4*)Xp;
    uint4 xa1 = *(const uint4*)(Xp + (size_t)32 * HH);
    uint4 xa2 = *(const uint4*)(Xp + (size_t)64 * HH);
    uint4 xa3 = *(const uint4*)(Xp + (size_t)96 * HH);
    uint4 wb0 = *(const uint4*)Wp;
    uint4 wb1 = *(const uint4*)(Wp + (size_t)32 * HH);
    uint4 wb2 = *(const uint4*)(Wp + (size_t)64 * HH);
    uint4 wb3 = *(const uint4*)(Wp + (size_t)96 * HH);
    f32x4 acc[4][4] = {};
    for (int k0 = 0; k0 < HH; k0 += 64) {
      if (k0) __syncthreads();
      *(uint4*)&As[r0 * 64 + ssw] = xa0;
      *(uint4*)&As[(r0 + 32) * 64 + ssw] = xa1;
      *(uint4*)&As[(r0 + 64) * 64 + ssw] = xa2;
      *(uint4*)&As[(r0 + 96) * 64 + ssw] = xa3;
      *(uint4*)&Bs[r0 * 64 + ssw] = wb0;
      *(uint4*)&Bs[(r0 + 32) * 64 + ssw] = wb1;
      *(uint4*)&Bs[(r0 + 64) * 64 + ssw] = wb2;
      *(uint4*)&Bs[(r0 + 96) * 64 + ssw] = wb3;
      __syncthreads();
      if (k0 + 64 < HH) {
        Xp += 64; Wp += 64;
        xa0 = *(const uint4*)Xp;
        xa1 = *(const uint4*)(Xp + (size_t)32 * HH);
        xa2 = *(const uint4*)(Xp + (size_t)64 * HH);
        xa3 = *(const uint4*)(Xp + (size_t)96 * HH);
        wb0 = *(const uint4*)Wp;
        wb1 = *(const uint4*)(Wp + (size_t)32 * HH);
        wb2 = *(const uint4*)(Wp + (size_t)64 * HH);
        wb3 = *(const uint4*)(Wp + (size_t)96 * HH);
      }
      bf16x8 af[4][2], bfr[4][2];
#pragma unroll
      for (int mt = 0; mt < 4; ++mt)
#pragma unroll
        for (int kt = 0; kt < 2; ++kt) {
          int row = wm + mt * 16 + lm, ch = lg + kt * 4;
          af[mt][kt] = *(bf16x8*)&As[row * 64 + ((ch ^ (row & 7)) * 8)];
        }
#pragma unroll
      for (int nt = 0; nt < 4; ++nt)
#pragma unroll
        for (int kt = 0; kt < 2; ++kt) {
          int row = wn + nt * 16 + lm, ch = lg + kt * 4;
          bfr[nt][kt] = *(bf16x8*)&Bs[row * 64 + ((ch ^ (row & 7)) * 8)];
        }
#pragma unroll
      for (int mt = 0; mt < 4; ++mt)
#pragma unroll
        for (int nt = 0; nt < 4; ++nt)
#pragma unroll
          for (int kt = 0; kt < 2; ++kt)
            acc[mt][nt] = __builtin_amdgcn_mfma_f32_16x16x32_bf16(af[mt][kt], bfr[nt][kt], acc[mt][nt], 0, 0, 0);
    }
    if (z == 2) {
#pragma unroll
      for (int nt = 0; nt < 4; ++nt) {
        int col = n0 + wn + nt * 16 + lm;
        int hh = col >> 6, dd = col & 63;
        float bcol = bias[col];
#pragma unroll
        for (int mt = 0; mt < 4; ++mt) {
          int row0 = m0 + wm + mt * 16 + lg * 4;
          int bb2 = row0 >> 10, nr = row0 & (NN - 1);
          ushort4 o;
          o.x = f2bf(acc[mt][nt][0] + bcol);
          o.y = f2bf(acc[mt][nt][1] + bcol);
          o.z = f2bf(acc[mt][nt][2] + bcol);
          o.w = f2bf(acc[mt][nt][3] + bcol);
          *(ushort4*)(C + ((size_t)(bb2 * NHD + hh) * ASZ + dd) * NN + nr) = o;
        }
      }
    } else {
#pragma unroll
      for (int nt = 0; nt < 4; ++nt) {
        int col = n0 + wn + nt * 16 + lm;
        float bcol = bias[col];
#pragma unroll
        for (int mt = 0; mt < 4; ++mt)
#pragma unroll
          for (int rr = 0; rr < 4; ++rr) {
            int row = m0 + wm + mt * 16 + lg * 4 + rr;
            C[(size_t)row * HH + col] = f2bf((acc[mt][nt][rr] + bcol) * alpha);
          }
      }
    }
  } else {
    // ---------------- score GEMM path ----------------
    const int bid2 = bid - GEMM_BLKS;
    const int b = bid2 / 72;
    const int rem = bid2 % 72;
    const int j0 = (rem / 12) * 64;
    const int n0g = (rem % 12) * 128;
    const int cnt = pcnt[b];
    if (j0 >= cnt) return;
    const bool symh = n0g >= HH;
    const int n0 = symh ? n0g - HH : n0g;
    const ushort* W = symh ? Wsym : Wvar;
    const float* bias = symh ? bsym : bvar;
    ushort* As = Sm;           // 64*64
    ushort* Bs = Sm + 4096;    // 128*64
    const int wm = (w >> 1) * 32, wn = (w & 1) * 64;
    if (t < 64) {
      int j = j0 + t;
      pl[t] = (j < cnt) ? plist[b * NN + j] : 2;
      red[t] = 0.f;
    }
    __syncthreads();
    const ushort* ap0; const ushort* ap1;
    if (symh) {
      const ushort* xbb = X + (size_t)b * NN * HH;
      ap0 = xbb + (size_t)pl[r0] * HH + c * 8;
      ap1 = xbb + (size_t)pl[r0 + 32] * HH + c * 8;
    } else {
      const ushort* vrb = vrows + ((size_t)b * PRMAX + j0) * HH;
      ap0 = vrb + (size_t)r0 * HH + c * 8;
      ap1 = vrb + (size_t)(r0 + 32) * HH + c * 8;
    }
    const ushort* bp = W + (size_t)(n0 + r0) * HH + c * 8;
    uint4 ar0 = *(const uint4*)ap0;
    uint4 ar1 = *(const uint4*)ap1;
    uint4 br0 = *(const uint4*)bp;
    uint4 br1 = *(const uint4*)(bp + (size_t)32 * HH);
    uint4 br2 = *(const uint4*)(bp + (size_t)64 * HH);
    uint4 br3 = *(const uint4*)(bp + (size_t)96 * HH);
    f32x4 acc[2][4] = {};
    for (int k0 = 0; k0 < HH; k0 += 64) {
      if (k0) __syncthreads();
      *(uint4*)&As[r0 * 64 + ssw] = ar0;
      *(uint4*)&As[(r0 + 32) * 64 + ssw] = ar1;
      *(uint4*)&Bs[r0 * 64 + ssw] = br0;
      *(uint4*)&Bs[(r0 + 32) * 64 + ssw] = br1;
      *(uint4*)&Bs[(r0 + 64) * 64 + ssw] = br2;
      *(uint4*)&Bs[(r0 + 96) * 64 + ssw] = br3;
      __syncthreads();
      if (k0 + 64 < HH) {
        ap0 += 64; ap1 += 64; bp += 64;
        ar0 = *(const uint4*)ap0;
        ar1 = *(const uint4*)ap1;
        br0 = *(const uint4*)bp;
        br1 = *(const uint4*)(bp + (size_t)32 * HH);
        br2 = *(const uint4*)(bp + (size_t)64 * HH);
        br3 = *(const uint4*)(bp + (size_t)96 * HH);
      }
      bf16x8 af[2][2], bfr[4][2];
#pragma unroll
      for (int mt = 0; mt < 2; ++mt)
#pragma unroll
        for (int kt = 0; kt < 2; ++kt) {
          int row = wm + mt * 16 + lm, ch = lg + kt * 4;
          af[mt][kt] = *(bf16x8*)&As[row * 64 + ((ch ^ (row & 7)) * 8)];
        }
#pragma unroll
      for (int nt = 0; nt < 4; ++nt)
#pragma unroll
        for (int kt = 0; kt < 2; ++kt) {
          int row = wn + nt * 16 + lm, ch = lg + kt * 4;
          bfr[nt][kt] = *(bf16x8*)&Bs[row * 64 + ((ch ^ (row & 7)) * 8)];
        }
#pragma unroll
      for (int mt = 0; mt < 2; ++mt)
#pragma unroll
        for (int nt = 0; nt < 4; ++nt)
#pragma unroll
          for (int kt = 0; kt < 2; ++kt)
            acc[mt][nt] = __builtin_amdgcn_mfma_f32_16x16x32_bf16(af[mt][kt], bfr[nt][kt], acc[mt][nt], 0, 0, 0);
    }
    float bcol[4], wcol[4];
#pragma unroll
    for (int nt = 0; nt < 4; ++nt) {
      int cl = wn + nt * 16 + lm;
      bcol[nt] = bias[n0 + cl];
      wcol[nt] = wscore[n0g + cl];
    }
#pragma unroll
    for (int mt = 0; mt < 2; ++mt)
#pragma unroll
      for (int rr = 0; rr < 4; ++rr) {
        float p = 0.f;
#pragma unroll
        for (int nt = 0; nt < 4; ++nt)
          p += fast_tanh(acc[mt][nt][rr] + bcol[nt]) * wcol[nt];
        p += __shfl_xor(p, 1); p += __shfl_xor(p, 2);
        p += __shfl_xor(p, 4); p += __shfl_xor(p, 8);
        if (lm == 0) atomicAdd(&red[wm + mt * 16 + lg * 4 + rr], p);
      }
    __syncthreads();
    if (t < 64) {
      int j2 = j0 + t;
      if (j2 < cnt) atomicAdd(&s_raw[b * NN + pl[t]], red[t]);
    }
  }
}

// ============ K_attn2: swapped-QK^T no-max flash attention ============
// 4 waves x 16 q-rows (64 q/block); KVBLK=64; exp2 domain, no max subtraction.
__global__ __launch_bounds__(256, 4) void k_attn2(
    const ushort* __restrict__ qg, const ushort* __restrict__ kg, const ushort* __restrict__ vtg,
    const float4* __restrict__ bias4, const int* __restrict__ pp, float* __restrict__ zz) {
  __shared__ ushort Ks[64 * 64];
  __shared__ ushort Vts[64 * 64];
  const int rb = blockIdx.y, h = blockIdx.x >> 3, b = blockIdx.x & 7;
  const int n0 = rb * 64;
  const int t = threadIdx.x, w = t >> 6, lane = t & 63, lg = lane >> 4, lm = lane & 15;
  const int qbase = n0 + w * 16;
  const ushort* qrow = qg + (size_t)(b * NN + qbase + lm) * HH + h * ASZ;
  bf16x8 qf[2];
  qf[0] = *(const bf16x8*)(qrow + lg * 8);
  qf[1] = *(const bf16x8*)(qrow + lg * 8 + 32);
  float4 bz = bias4[b * NN + qbase + lm];
  const int cwq = __float_as_int(bz.x);
  f32x4 suml = {0.f, 0.f, 0.f, 0.f};   // per-lane partial l (reduced in epilogue)
  f32x4 y[4] = {};
  const ushort* kb = kg + (size_t)(b * NN) * HH + h * ASZ;
  const ushort* vtb = vtg + (size_t)(b * NHD + h) * ASZ * NN;
  const int srow = t >> 3, sc = t & 7;
  const int arow = (srow & 35) | ((srow & 4) << 2) | ((srow & 24) >> 1);  // 6-bit perm
  const int kssw = (sc ^ (arow & 7)) * 8;
  const int vssw = (sc ^ (srow & 7)) * 8;
  const ushort* kptr = kb + (size_t)srow * HH + sc * 8;
  const ushort* vptr = vtb + (size_t)srow * NN + sc * 8;
  uint4 ka = *(const uint4*)kptr;
  uint4 kc = *(const uint4*)(kptr + (size_t)32 * HH);
  uint4 va = *(const uint4*)vptr;
  uint4 vb2 = *(const uint4*)(vptr + (size_t)32 * NN);
  for (int tile = 0; tile < 16; ++tile) {
    const int c0 = tile * 64;
    *(uint4*)&Ks[arow * 64 + kssw] = ka;
    *(uint4*)&Ks[(arow + 32) * 64 + kssw] = kc;
    *(uint4*)&Vts[srow * 64 + vssw] = va;
    *(uint4*)&Vts[(srow + 32) * 64 + vssw] = vb2;
    __syncthreads();
    if (tile < 15) {   // prefetch next tile into registers
      kptr += (size_t)64 * HH; vptr += 64;
      ka = *(const uint4*)kptr;
      kc = *(const uint4*)(kptr + (size_t)32 * HH);
      va = *(const uint4*)vptr;
      vb2 = *(const uint4*)(vptr + (size_t)32 * NN);
    }
    f32x4 s[4] = {};
    __builtin_amdgcn_s_setprio(1);
#pragma unroll
    for (int nt = 0; nt < 4; ++nt) {
      int krow = lm + nt * 16, sw = krow & 7;
#pragma unroll
      for (int kt = 0; kt < 2; ++kt) {
        bf16x8 kf = *(bf16x8*)&Ks[krow * 64 + (((lg + kt * 4) ^ sw) * 8)];
        s[nt] = __builtin_amdgcn_mfma_f32_16x16x32_bf16(kf, qf[kt], s[nt], 0, 0, 0);
      }
    }
    __builtin_amdgcn_s_setprio(0);
    // sparse bias: token of s[nt][r] = c0 + (nt>>1)*32 + lg*8 + (nt&1)*4 + r
    if (c0 <= qbase + 17 && qbase <= c0 + 65) {
#pragma unroll
      for (int nt = 0; nt < 4; ++nt) {
        int kb2 = c0 + (nt >> 1) * 32 + lg * 8 + (nt & 1) * 4;
#pragma unroll
        for (int r = 0; r < 4; ++r) {
          int dd = kb2 + r - cwq;
          if (dd >= 0 && dd < 3) s[nt][r] += (dd == 0) ? bz.y : (dd == 1 ? bz.z : bz.w);
        }
      }
    }
    // no-max exp: p = 2^s directly (bounded logits); accumulate per-lane l
#pragma unroll
    for (int nt = 0; nt < 4; ++nt)
#pragma unroll
      for (int e = 0; e < 4; ++e) {
        float p = EXP2F(s[nt][e]);
        s[nt][e] = p;
        suml[e] += p;
      }
    // pack P into PV A-frags via v_perm (register-local)
    union { unsigned u[4]; bf16x8 v; } pk[2];
#pragma unroll
    for (int kt = 0; kt < 2; ++kt) {
      pk[kt].u[0] = packbf2(s[2 * kt][0], s[2 * kt][1]);
      pk[kt].u[1] = packbf2(s[2 * kt][2], s[2 * kt][3]);
      pk[kt].u[2] = packbf2(s[2 * kt + 1][0], s[2 * kt + 1][1]);
      pk[kt].u[3] = packbf2(s[2 * kt + 1][2], s[2 * kt + 1][3]);
    }
    __builtin_amdgcn_s_setprio(1);
#pragma unroll
    for (int nt = 0; nt < 4; ++nt) {
      int vrow = lm + nt * 16, sw = vrow & 7;
#pragma unroll
      for (int kt = 0; kt < 2; ++kt) {
        bf16x8 vf = *(bf16x8*)&Vts[vrow * 64 + (((lg + kt * 4) ^ sw) * 8)];
        y[nt] = __builtin_amdgcn_mfma_f32_16x16x32_bf16(pk[kt].v, vf, y[nt], 0, 0, 0);
      }
    }
    __builtin_amdgcn_s_setprio(0);
    __syncthreads();
  }
  // epilogue: reduce l once, then weighted row-sums into z1/z2
  float ts = (suml[0] + suml[1]) + (suml[2] + suml[3]);
  ts += __shfl_xor(ts, 16);
  ts += __shfl_xor(ts, 32);
  float invl = 1.f / ts;                 // l for q = qbase+lm
  float invq[4], c1v[4], c2v[4];
#pragma unroll
  for (int r = 0; r < 4; ++r) {
    invq[r] = __shfl(invl, lg * 4 + r);
    coefs(pp + b * NN, qbase + lg * 4 + r, c1v[r], c2v[r]);
  }
  float a1[4], a2[4];
#pragma unroll
  for (int nt = 0; nt < 4; ++nt) {
    float u1 = 0.f, u2 = 0.f;
#pragma unroll
    for (int r = 0; r < 4; ++r) {
      float yv = y[nt][r] * invq[r];
      u1 += c1v[r] * yv;
      u2 += c2v[r] * yv;
    }
    u1 += __shfl_xor(u1, 16); u1 += __shfl_xor(u1, 32);
    u2 += __shfl_xor(u2, 16); u2 += __shfl_xor(u2, 32);
    a1[nt] = u1; a2[nt] = u2;
  }
  if (lg == 0) {
#pragma unroll
    for (int nt = 0; nt < 4; ++nt) {
      atomicAdd(&zz[b * HH + h * ASZ + nt * 16 + lm], a1[nt]);
      atomicAdd(&zz[BB * HH + b * HH + h * ASZ + nt * 16 + lm], a2[nt]);
    }
  }
}

// ============ F1: t_s = W_o @ (z_s / sumw) + b_o ============
__global__ void k_f1(const float* __restrict__ Wo, const float* __restrict__ bo,
                     const float* __restrict__ zz, const float* __restrict__ sumw,
                     float* __restrict__ tvec) {
  int b = blockIdx.y;
  int w = threadIdx.x >> 6, lane = threadIdx.x & 63;
  float inv = 1.f / sumw[b];
  const float* z1 = zz + b * HH;
  const float* z2 = zz + BB * HH + b * HH;
  float zr1[12], zr2[12];
#pragma unroll
  for (int m = 0; m < 12; ++m) { zr1[m] = z1[lane + 64 * m] * inv; zr2[m] = z2[lane + 64 * m] * inv; }
  for (int j = 0; j < 8; ++j) {
    int o = blockIdx.x * 32 + w * 8 + j;
    const float* wrow = Wo + (size_t)o * HH;
    float a1 = 0.f, a2 = 0.f;
#pragma unroll
    for (int m = 0; m < 12; ++m) { float wv = wrow[lane + 64 * m]; a1 += wv * zr1[m]; a2 += wv * zr2[m]; }
    for (int mask = 32; mask; mask >>= 1) { a1 += __shfl_xor(a1, mask); a2 += __shfl_xor(a2, mask); }
    if (lane == 0) { tvec[b * HH + o] = a1 + bo[o]; tvec[BB * HH + b * HH + o] = a2 + bo[o]; }
  }
}

// ============ F2: pm = WL @ t1 + WR @ t2 + b_atom ============
__global__ void k_f2(const float* __restrict__ Wa, const float* __restrict__ ba,
                     const float* __restrict__ tvec, float* __restrict__ pm) {
  int b = blockIdx.y;
  int w = threadIdx.x >> 6, lane = threadIdx.x & 63;
  const float* t1 = tvec + b * HH;
  const float* t2 = tvec + BB * HH + b * HH;
  float r1[12], r2[12];
#pragma unroll
  for (int m = 0; m < 12; ++m) { r1[m] = t1[lane + 64 * m]; r2[m] = t2[lane + 64 * m]; }
  for (int j = 0; j < 8; ++j) {
    int o = blockIdx.x * 32 + w * 8 + j;
    const float* wrow = Wa + (size_t)o * (2 * HH);
    float a = 0.f;
#pragma unroll
    for (int m = 0; m < 12; ++m) a += wrow[lane + 64 * m] * r1[m];
#pragma unroll
    for (int m = 0; m < 12; ++m) a += wrow[HH + lane + 64 * m] * r2[m];
    for (int mask = 32; mask; mask >>= 1) a += __shfl_xor(a, mask);
    if (lane == 0) pm[b * HH + o] = a + ba[o];
  }
}

// ============ F3: broadcast pm to (B,N,H) ============
__global__ void k_bcast(const float* __restrict__ pm, float* __restrict__ out) {
  size_t g = (size_t)blockIdx.x * 256 + threadIdx.x;
  int b = (int)(g / ((size_t)NN * HH / 4));
  int hh4 = (int)(g % (HH / 4));
  float4 val = *(const float4*)(pm + b * HH + hh4 * 4);
  *(float4*)(out + g * 4) = val;
}

// ================= launcher =================
extern "C" void kernel_launch(void* const* d_in, const int* in_sizes, int n_in,
                              void* d_out, int out_size, void* d_ws, size_t ws_size,
                              hipStream_t stream) {
  (void)in_sizes; (void)n_in; (void)out_size; (void)ws_size;
  const float* x       = (const float*)d_in[0];
  const float* W_var   = (const float*)d_in[3];
  const float* b_var   = (const float*)d_in[4];
  const float* W_sym   = (const float*)d_in[5];
  const float* b_sym   = (const float*)d_in[6];
  const float* W_score = (const float*)d_in[7];
  const float* b_score = (const float*)d_in[8];
  const float* W_cross = (const float*)d_in[9];
  const float* b_cross = (const float*)d_in[10];
  const float* W_atom  = (const float*)d_in[11];
  const float* b_atom  = (const float*)d_in[12];
  const float* W_q     = (const float*)d_in[13];
  const float* b_q     = (const float*)d_in[14];
  const float* W_k     = (const float*)d_in[15];
  const float* b_k     = (const float*)d_in[16];
  const float* W_v     = (const float*)d_in[17];
  const float* b_v     = (const float*)d_in[18];
  const float* W_o     = (const float*)d_in[19];
  const float* b_o     = (const float*)d_in[20];
  const int*   pp      = (const int*)d_in[21];
  const int*   occ     = (const int*)d_in[24];
  float* out = (float*)d_out;
  char* wsb = (char*)d_ws;
  ushort* qb  = (ushort*)(wsb + OFFB_QB);
  ushort* kbf = (ushort*)(wsb + OFFB_KB);
  ushort* vtb = (ushort*)(wsb + OFFB_VB);
  ushort* xb  = (ushort*)(wsb + OFFB_XB);
  ushort* wqb = (ushort*)(wsb + OFFB_WQB);
  ushort* wkb = (ushort*)(wsb + OFFB_WKB);
  ushort* wvb = (ushort*)(wsb + OFFB_WVB);
  ushort* wvar = (ushort*)(wsb + OFFB_WVAR);
  ushort* wsym = (ushort*)(wsb + OFFB_WSYM);
  ushort* vrows = (ushort*)(wsb + OFFB_VROWS);
  float* sraw = (float*)(wsb + OFFB_SRAW);
  float* diag = (float*)(wsb + OFFB_DIAG);
  float4* bias4 = (float4*)(wsb + OFFB_BIAS4);
  int* plist = (int*)(wsb + OFFB_PLIST);
  int* pcnt  = (int*)(wsb + OFFB_PCNT);
  float* sumw = (float*)(wsb + OFFB_SUMW);
  float* zz   = (float*)(wsb + OFFB_ZZ);
  float* tv   = (float*)(wsb + OFFB_TV);
  float* pm   = (float*)(wsb + OFFB_PM);

  k_pred<<<BB, 64, 0, stream>>>(pp, plist, pcnt, sumw, sraw, diag, zz);
  // f32->bf16 (x + 5 weights) fused with occurrence-pair scores
  k_cvtall<<<NCVT + BB * MM / 4, 256, 0, stream>>>(
      x, W_q, W_k, W_v, W_var, W_sym, xb, wqb, wkb, wvb, wvar, wsym,
      occ, W_cross, b_cross, diag);
  // gather var_in rows (bf16, compact)
  k_gather<<<dim3(PRMAX / 4, BB), 256, 0, stream>>>(xb, pp, plist, pcnt, vrows);
  // fused QKV GEMM + score GEMM (independent, co-scheduled)
  k_mats<<<MATS_BLKS, 256, 0, stream>>>(
      xb, vrows, plist, pcnt, wvar, wsym, b_var, b_sym, W_score, sraw,
      wqb, wkb, wvb, b_q, b_k, b_v, qb, kbf, vtb);
  k_bias<<<BB * NN / 256, 256, 0, stream>>>(pp, sraw, diag, b_score, bias4);
  // MFMA flash attention (64 q-rows/block, 4 waves, no-max exp2 softmax)
  k_attn2<<<dim3(NHD * BB, NN / 64), 256, 0, stream>>>(qb, kbf, vtb, bias4, pp, zz);
  k_f1<<<dim3(24, BB), 256, 0, stream>>>(W_o, b_o, zz, sumw, tv);
  k_f2<<<dim3(24, BB), 256, 0, stream>>>(W_atom, b_atom, tv, pm);
  k_bcast<<<BB * NN * HH / 1024, 256, 0, stream>>>(pm, out);
}